// Round 6
// baseline (333.682 us; speedup 1.0000x reference)
//
#include <hip/hip_runtime.h>

#define NVOX 200000
#define KOFF 9
#define NSHARD 32
#define BN_EPS 1e-5f

typedef unsigned short u16;
typedef __bf16 bf16x8 __attribute__((ext_vector_type(8)));
typedef u16 u16x8 __attribute__((ext_vector_type(8)));
typedef float f32x4 __attribute__((ext_vector_type(4)));

__device__ __forceinline__ float lrelu(float x) { return x > 0.0f ? x : 0.01f * x; }
__device__ __forceinline__ float bf2f(u16 h) { return __uint_as_float(((unsigned)h) << 16); }
__device__ __forceinline__ u16 f2bf(float x) {   // round-nearest-even
    unsigned u = __float_as_uint(x);
    u += 0x7fffu + ((u >> 16) & 1u);
    return (u16)(u >> 16);
}
__device__ __forceinline__ unsigned pkbf(float a, float b) {
    return (unsigned)f2bf(a) | ((unsigned)f2bf(b) << 16);
}

// Barrier-free MFMA sparse-conv:
//  - lane gathers its A-fragment DIRECTLY global->register (16B loads), no LDS
//    staging, no barriers in the K-loop -> deep ILP across 9 offsets x 4 M-tiles
//  - neighbor indices: one coalesced load per k (lane l <-> row l) + __shfl
//  - folded-BN bias via register-built 0/1 mask fragment MFMA
//  - epilogue: acc -> LDS tile -> full-line coalesced global stores (fixes 3x
//    write amplification), shfl-reduced BN stats -> 32-way sharded atomics
// 64 voxels x 64 cout per block, 4 waves; wave w owns cols 16w..16w+15.
template<int CIN, bool BIAS>
__global__ __launch_bounds__(256, 4) void conv_mfma(
    const u16* __restrict__ X0, const u16* __restrict__ X1,
    const int* __restrict__ nbr0, const int* __restrict__ nbr1,
    const int* __restrict__ msk0, const int* __restrict__ msk1,
    const u16* __restrict__ Wt,           // [2][KOFF][64][CIN] bf16
    const u16* __restrict__ BWt,          // [2][64][32] bf16 (BIAS only)
    u16* __restrict__ outH0, u16* __restrict__ outH1,
    float* __restrict__ outF0, float* __restrict__ outF1,
    float* __restrict__ st0, float* __restrict__ st1)
{
    constexpr int NLD = CIN / 32;          // bf16x8 A-loads per (k, mt)
    const int br = blockIdx.y;
    const u16* X = br ? X1 : X0;
    const int* nbr = br ? nbr1 : nbr0;
    const int* msk = br ? msk1 : msk0;
    const u16* Wg = Wt + (size_t)br * KOFF * 64 * CIN;
    u16* outH = br ? outH1 : outH0;
    float* outF = br ? outF1 : outF0;
    float* st = br ? st1 : st0;

    // output staging: u16 tile [64][72] (9216B) or f32 tile [64][68] (17408B)
    __shared__ __align__(16) unsigned char sraw[17408 + 512];
    u16*   sO16 = (u16*)sraw;
    float* sO32 = (float*)sraw;
    float* red  = (float*)(sraw + 17408);

    const int tid = threadIdx.x;
    const int n0 = blockIdx.x * 64;
    const int wv = tid >> 6;
    const int l  = tid & 63;
    const int rl = l & 15;
    const int q  = l >> 4;
    const int colbase = wv * 16;

    // ---- per-lane neighbor indices: lane l <-> tile row l (coalesced, mask folded)
    int src9[KOFF];
    #pragma unroll
    for (int k = 0; k < KOFF; ++k) {
        const int m  = msk[k * NVOX + n0 + l];
        const int nb = nbr[k * NVOX + n0 + l];
        src9[k] = m ? nb : -1;
    }

    // ---- weight B-fragments (L2-hot; compiler rematerializes under VGPR cap)
    bf16x8 wreg[KOFF][NLD];
    #pragma unroll
    for (int k = 0; k < KOFF; ++k)
        #pragma unroll
        for (int ch = 0; ch < NLD; ++ch)
            wreg[k][ch] = *(const bf16x8*)(Wg + ((size_t)k * 64 + colbase + rl) * CIN
                                           + ch * 32 + q * 8);

    // ---- barrier-free gather + MFMA over 9 offsets x 4 M-tiles
    f32x4 acc[4] = {};
    int mbits[4] = {0, 0, 0, 0};
    #pragma unroll
    for (int k = 0; k < KOFF; ++k) {
        #pragma unroll
        for (int mt = 0; mt < 4; ++mt) {
            const int src = __shfl(src9[k], mt * 16 + rl, 64);
            if constexpr (BIAS) mbits[mt] |= (src >= 0) ? (1 << k) : 0;
            #pragma unroll
            for (int ch = 0; ch < NLD; ++ch) {
                uint4 gv = make_uint4(0u, 0u, 0u, 0u);
                if (src >= 0)
                    gv = *(const uint4*)(X + (size_t)src * CIN + ch * 32 + q * 8);
                bf16x8 afr = __builtin_bit_cast(bf16x8, gv);
                acc[mt] = __builtin_amdgcn_mfma_f32_16x16x32_bf16(afr, wreg[k][ch], acc[mt], 0, 0, 0);
            }
        }
    }

    // ---- folded-BN bias via mask MFMA: acc += M(mask 0/1) x BW
    if constexpr (BIAS) {
        bf16x8 bw = *(const bf16x8*)(BWt + ((size_t)br * 64 + colbase + rl) * 32 + q * 8);
        #pragma unroll
        for (int mt = 0; mt < 4; ++mt) {
            u16x8 mu;
            #pragma unroll
            for (int j = 0; j < 8; ++j) {
                const int k = q * 8 + j;
                mu[j] = (k < KOFF && ((mbits[mt] >> k) & 1)) ? (u16)0x3F80 : (u16)0;
            }
            bf16x8 mf = __builtin_bit_cast(bf16x8, mu);
            acc[mt] = __builtin_amdgcn_mfma_f32_16x16x32_bf16(mf, bw, acc[mt], 0, 0, 0);
        }
    }

    // ---- epilogue: LeakyReLU -> LDS tile + BN partials
    float ps = 0.f, pss = 0.f;
    #pragma unroll
    for (int mt = 0; mt < 4; ++mt) {
        #pragma unroll
        for (int i = 0; i < 4; ++i) {
            float v = lrelu(acc[mt][i]);
            ps += v; pss += v * v;
            const int row = mt * 16 + q * 4 + i;
            if (outH) sO16[row * 72 + colbase + rl] = f2bf(v);
            else      sO32[row * 68 + colbase + rl] = v;
        }
    }
    ps  += __shfl_xor(ps, 16);  ps  += __shfl_xor(ps, 32);
    pss += __shfl_xor(pss, 16); pss += __shfl_xor(pss, 32);
    if (l < 16) { red[colbase + rl] = ps; red[64 + colbase + rl] = pss; }
    __syncthreads();

    // ---- coalesced full-line stores + sharded stat atomics
    if (outH) {
        #pragma unroll
        for (int p = 0; p < 2; ++p) {
            const int row = (tid >> 3) + p * 32, seg = tid & 7;
            uint4 v = *(const uint4*)(sO16 + row * 72 + seg * 8);
            *(uint4*)(outH + (size_t)(n0 + row) * 64 + seg * 8) = v;
        }
    } else {
        #pragma unroll
        for (int p = 0; p < 4; ++p) {
            const int row = (tid >> 4) + p * 16, seg = tid & 15;
            float4 v = *(const float4*)(sO32 + row * 68 + seg * 4);
            *(float4*)(outF + (size_t)(n0 + row) * 64 + seg * 4) = v;
        }
    }
    if (tid < 128) {
        const int shard = blockIdx.x & (NSHARD - 1);
        atomicAdd(st + shard * 512 + (tid >> 6) * 64 + (tid & 63), red[tid]);
    }
}

// b<144: WtA[br][k][d][c]=bf16(W[k][c][d]);  b in [144,208): zero sharded stats;
// b>=208: feats f32 -> bf16 (into feats16), grid-stride.
__global__ void prep0(const float* __restrict__ W1, const float* __restrict__ W2,
                      const float* __restrict__ feats,
                      u16* __restrict__ WtA, float* __restrict__ stats,
                      u16* __restrict__ feats16)
{
    const int b = blockIdx.x;
    const int t = threadIdx.x;
    if (b < 144) {
        const int i = b * 256 + t;                 // 2*9*64*32 = 36864 exactly
        const int brw = i / (KOFF * 64 * 32);
        const int r  = i % (KOFF * 64 * 32);
        const int k  = r / (64 * 32);
        const int r2 = r % (64 * 32);
        const int d  = r2 / 32, c = r2 % 32;
        const float* W = brw ? W2 : W1;
        WtA[i] = f2bf(W[((size_t)k * 32 + c) * 64 + d]);
        return;
    }
    if (b < 208) {                                 // 64*256 = 16384 = NSHARD*512
        stats[(b - 144) * 256 + t] = 0.f;
        return;
    }
    const int stride = (gridDim.x - 208) * 256;
    for (int i = (b - 208) * 256 + t; i < NVOX * 32 / 8; i += stride) {
        const float4 f0 = ((const float4*)feats)[i * 2];
        const float4 f1 = ((const float4*)feats)[i * 2 + 1];
        ((uint4*)feats16)[i] = make_uint4(pkbf(f0.x, f0.y), pkbf(f0.z, f0.w),
                                          pkbf(f1.x, f1.y), pkbf(f1.z, f1.w));
    }
}

// finalize stage-A BN (sum shards, in LDS) + fold into stage-B weights:
// WtB[br][k][d][c] = bf16(W[k][c][d]*a[c]); BWt[br][d][k(pad32)] = bf16(sum_c b'[c]*W[k][c][d])
__global__ void wprepB(const float* __restrict__ W12, const float* __restrict__ W3,
                       const float* __restrict__ stats,
                       const float* __restrict__ g0, const float* __restrict__ b0,
                       const float* __restrict__ g1, const float* __restrict__ b1,
                       u16* __restrict__ WtB, u16* __restrict__ BWt)
{
    __shared__ float sa[256];                 // [br][{a[64], b'[64]}]
    const int t = threadIdx.x;
    if (t < 128) {
        const int brw = t >> 6, d = t & 63;
        float s = 0.f, ss = 0.f;
        for (int sh = 0; sh < NSHARD; ++sh) {
            s  += stats[sh * 512 + brw * 128 + d];
            ss += stats[sh * 512 + brw * 128 + 64 + d];
        }
        const float* g = brw ? g1 : g0;
        const float* bb = brw ? b1 : b0;
        const float inv_n = 1.0f / (float)NVOX;
        float mu  = s * inv_n;
        float var = ss * inv_n - mu * mu;
        float a = g[d] * rsqrtf(var + BN_EPS);
        sa[brw * 128 + d] = a;
        sa[brw * 128 + 64 + d] = bb[d] - mu * a;
    }
    __syncthreads();
    const int i = blockIdx.x * 256 + t;
    if (i >= 2 * KOFF * 64) return;
    const int brw = i / (KOFF * 64);
    const int r  = i % (KOFF * 64);
    const int k  = r / 64, d = r % 64;
    const float* W = brw ? W3 : W12;
    const float* a = sa + brw * 128;
    const float* bb = a + 64;
    float bw = 0.f;
    u16* wrow = WtB + (((size_t)brw * KOFF + k) * 64 + d) * 64;
    #pragma unroll 8
    for (int c = 0; c < 64; ++c) {
        const float wv = W[((size_t)k * 64 + c) * 64 + d];
        wrow[c] = f2bf(wv * a[c]);
        bw += wv * bb[c];
    }
    u16* brow = BWt + ((size_t)brw * 64 + d) * 32;
    brow[k] = f2bf(bw);
    if (k == 0) {
        for (int kk = KOFF; kk < 32; ++kk) brow[kk] = 0;
    }
}

// finalize stage-B BN (sum shards) + out = aff2(ys) + aff3(yr), in place over yr (= d_out)
__global__ void combine_kernel(const u16* __restrict__ ys, float* __restrict__ yr,
                               const float* __restrict__ stats,
                               const float* __restrict__ g02, const float* __restrict__ b02,
                               const float* __restrict__ g2, const float* __restrict__ b2)
{
    __shared__ float sc[256];                 // [br][{a[64], b'[64]}]; br0=ys, br1=yr
    const int t = threadIdx.x;
    if (t < 128) {
        const int brw = t >> 6, d = t & 63;
        float s = 0.f, ss = 0.f;
        for (int sh = 0; sh < NSHARD; ++sh) {
            s  += stats[sh * 512 + 256 + brw * 128 + d];
            ss += stats[sh * 512 + 256 + brw * 128 + 64 + d];
        }
        const float* g = brw ? g2 : g02;
        const float* b = brw ? b2 : b02;
        const float inv_n = 1.0f / (float)NVOX;
        float mu  = s * inv_n;
        float var = ss * inv_n - mu * mu;
        float a = g[d] * rsqrtf(var + BN_EPS);
        sc[brw * 128 + d] = a;
        sc[brw * 128 + 64 + d] = b[d] - mu * a;
    }
    __syncthreads();
    const int total = NVOX * 64 / 4;
    for (int i = blockIdx.x * blockDim.x + t; i < total; i += gridDim.x * blockDim.x) {
        const int dq = (i & 15) * 4;
        ushort4 sh = reinterpret_cast<const ushort4*>(ys)[i];
        float4 r = reinterpret_cast<const float4*>(yr)[i];
        float4 a2 = *(const float4*)(sc + dq);
        float4 b2v = *(const float4*)(sc + 64 + dq);
        float4 a3 = *(const float4*)(sc + 128 + dq);
        float4 b3v = *(const float4*)(sc + 128 + 64 + dq);
        float4 o;
        o.x = fmaf(a2.x, bf2f(sh.x), b2v.x) + fmaf(a3.x, r.x, b3v.x);
        o.y = fmaf(a2.y, bf2f(sh.y), b2v.y) + fmaf(a3.y, r.y, b3v.y);
        o.z = fmaf(a2.z, bf2f(sh.z), b2v.z) + fmaf(a3.z, r.z, b3v.z);
        o.w = fmaf(a2.w, bf2f(sh.w), b2v.w) + fmaf(a3.w, r.w, b3v.w);
        reinterpret_cast<float4*>(yr)[i] = o;
    }
}

extern "C" void kernel_launch(void* const* d_in, const int* in_sizes, int n_in,
                              void* d_out, int out_size, void* d_ws, size_t ws_size,
                              hipStream_t stream) {
    const float* feats = (const float*)d_in[0];
    const float* W1    = (const float*)d_in[1];
    const float* W12   = (const float*)d_in[2];
    const float* W2    = (const float*)d_in[3];
    const float* W3    = (const float*)d_in[4];
    const float* g0  = (const float*)d_in[5];
    const float* b0  = (const float*)d_in[6];
    const float* g02 = (const float*)d_in[7];
    const float* b02 = (const float*)d_in[8];
    const float* g1  = (const float*)d_in[9];
    const float* b1  = (const float*)d_in[10];
    const float* g2  = (const float*)d_in[11];
    const float* b2  = (const float*)d_in[12];
    const int* nbrA  = (const int*)d_in[13];
    const int* maskA = (const int*)d_in[14];   // bool delivered as int32
    const int* nbrB  = (const int*)d_in[15];
    const int* maskB = (const int*)d_in[16];

    // ws layout: bf16 activations + bf16 weights + sharded f32 stats (~77 MB).
    // feats16 aliases ys: feats16 read only in stage A, ys written only in stage B.
    const size_t buf = (size_t)NVOX * 64;
    u16* y1  = (u16*)d_ws;
    u16* y2  = y1 + buf;
    u16* ys  = y2 + buf;
    u16* feats16 = ys;                   // alias (NVOX*32 u16)
    u16* WtA = ys + buf;                 // 2*9*64*32 = 36864
    u16* WtB = WtA + 2 * KOFF * 64 * 32; // 2*9*64*64 = 73728
    u16* BWt = WtB + 2 * KOFF * 64 * 64; // 2*64*32   = 4096
    float* stats = (float*)(BWt + 2 * 64 * 32);  // NSHARD x [4 x {sum[64],sumsq[64]}]
    float* outf  = (float*)d_out;        // stage-B resA output lives in d_out

    dim3 gA(NVOX / 64, 2);

    prep0<<<2000, 256, 0, stream>>>(W1, W2, feats, WtA, stats, feats16);

    // stage A: y1 = lrelu(conv(feats,nbrA,W1)); y2 = lrelu(conv(feats,nbrB,W2))
    conv_mfma<32, false><<<gA, 256, 0, stream>>>(
        feats16, feats16, nbrA, nbrB, maskA, maskB, WtA, nullptr,
        y1, y2, nullptr, nullptr, stats, stats + 128);

    wprepB<<<5, 256, 0, stream>>>(W12, W3, stats, g0, b0, g1, b1, WtB, BWt);

    // stage B: ys = lrelu(conv(bn(y1),nbrB,W12)); outf = lrelu(conv(bn(y2),nbrA,W3))
    conv_mfma<64, true><<<gA, 256, 0, stream>>>(
        y1, y2, nbrB, nbrA, maskB, maskA, WtB, BWt,
        ys, nullptr, nullptr, outf, stats + 256, stats + 384);

    combine_kernel<<<1024, 256, 0, stream>>>(ys, outf, stats, g02, b02, g2, b2);
}

// Round 7
// 179.253 us; speedup vs baseline: 1.8615x; 1.8615x over previous
//
#include <hip/hip_runtime.h>

#define NVOX 200000
#define KOFF 9
#define NSHARD 32
#define BN_EPS 1e-5f

typedef unsigned short u16;
typedef __bf16 bf16x8 __attribute__((ext_vector_type(8)));
typedef float f32x4 __attribute__((ext_vector_type(4)));

__device__ __forceinline__ float lrelu(float x) { return x > 0.0f ? x : 0.01f * x; }
__device__ __forceinline__ float bf2f(u16 h) { return __uint_as_float(((unsigned)h) << 16); }
__device__ __forceinline__ u16 f2bf(float x) {   // round-nearest-even
    unsigned u = __float_as_uint(x);
    u += 0x7fffu + ((u >> 16) & 1u);
    return (u16)(u >> 16);
}
__device__ __forceinline__ unsigned pkbf(float a, float b) {
    return (unsigned)f2bf(a) | ((unsigned)f2bf(b) << 16);
}

// MFMA sparse-conv (r5 ring pipeline + LDS-tile store epilogue):
//  - all 9 mask/nbr indices preloaded (independent loads)
//  - gather ring: 3 LDS slots, loads for offset k issued at iteration k-2
//    (2 reg sets in flight), ONE barrier per iteration
//  - BN stats: 32-way sharded atomics
//  - epilogue: acc -> LDS tile -> full-128B-line coalesced stores (kills the
//    3x partial-line write amplification seen in r5)
// 64 voxels x 64 cout per block, 4 waves; wave w owns cols 16w..16w+15.
template<int CIN, bool BIAS>
__global__ __launch_bounds__(256, 4) void conv_mfma(
    const u16* __restrict__ X0, const u16* __restrict__ X1,
    const int* __restrict__ nbr0, const int* __restrict__ nbr1,
    const int* __restrict__ msk0, const int* __restrict__ msk1,
    const u16* __restrict__ Wt,           // [2][KOFF][64][CIN] bf16
    const u16* __restrict__ BWt,          // [2][64][32] bf16 (BIAS only)
    u16* __restrict__ outH0, u16* __restrict__ outH1,
    float* __restrict__ outF0, float* __restrict__ outF1,
    float* __restrict__ st0, float* __restrict__ st1)
{
    constexpr int GSTR = CIN + 8;          // bf16 row pitch (16B-aligned)
    constexpr int NLD = CIN / 32;          // uint4 gather loads per thread (1 or 2)
    const int br = blockIdx.y;
    const u16* X = br ? X1 : X0;
    const int* nbr = br ? nbr1 : nbr0;
    const int* msk = br ? msk1 : msk0;
    const u16* Wg = Wt + (size_t)br * KOFF * 64 * CIN;
    u16* outH = br ? outH1 : outH0;
    float* outF = br ? outF1 : outF0;
    float* st = br ? st1 : st0;

    __shared__ __align__(16) u16 sG[3][64 * GSTR];
    __shared__ __align__(16) u16 sM[BIAS ? 64 * 32 : 8];
    __shared__ float red[128];

    const int tid = threadIdx.x;
    const int n0 = blockIdx.x * 64;
    const int wv = tid >> 6;
    const int l  = tid & 63;
    const int rl = l & 15;
    const int q  = l >> 4;
    const int colbase = wv * 16;
    const int gr = tid >> 2;        // gather: 4 threads per row
    const int gc = tid & 3;

    // ---- preload all neighbor indices (mask folded to -1)
    int srcs[KOFF];
    #pragma unroll
    for (int k = 0; k < KOFF; ++k) {
        const int m  = msk[k * NVOX + n0 + gr];
        const int nb = nbr[k * NVOX + n0 + gr];
        srcs[k] = m ? nb : -1;
    }

    // ---- mask matrix for folded-BN bias MFMA (visible after loop barriers)
    if constexpr (BIAS) {
        #pragma unroll
        for (int j = 0; j < 8; ++j) {
            const int k = gc * 8 + j;
            sM[gr * 32 + k] = ((k < KOFF) && (srcs[k] >= 0)) ? (u16)0x3F80 : (u16)0;
        }
    }

    // ---- weight B-fragments (L2-hot; compiler may rematerialize under VGPR cap)
    bf16x8 wreg[KOFF][NLD];
    #pragma unroll
    for (int k = 0; k < KOFF; ++k)
        #pragma unroll
        for (int ch = 0; ch < NLD; ++ch)
            wreg[k][ch] = *(const bf16x8*)(Wg + ((size_t)k * 64 + colbase + rl) * CIN
                                           + ch * 32 + q * 8);

    uint4 g[2][NLD];
    auto issue = [&](int k, int s) {
        const int src = srcs[k];
        #pragma unroll
        for (int c = 0; c < NLD; ++c) g[s][c] = make_uint4(0u, 0u, 0u, 0u);
        if (src >= 0) {
            const u16* p = X + (size_t)src * CIN + gc * (CIN / 4);
            #pragma unroll
            for (int c = 0; c < NLD; ++c) g[s][c] = ((const uint4*)p)[c];
        }
    };
    auto store_s = [&](int k, int s) {
        u16* d = &sG[k % 3][gr * GSTR + gc * (CIN / 4)];
        #pragma unroll
        for (int c = 0; c < NLD; ++c) ((uint4*)d)[c] = g[s][c];
    };

    f32x4 acc[4] = {};
    issue(0, 0);
    issue(1, 1);
    #pragma unroll
    for (int k = 0; k < KOFF; ++k) {
        store_s(k, k & 1);                 // waits this set's loads; frees the set
        __syncthreads();                   // slot k%3 visible to all waves
        if (k + 2 < KOFF) issue(k + 2, k & 1);
        const u16* sgb = &sG[k % 3][0];
        #pragma unroll
        for (int mt = 0; mt < 4; ++mt)
            #pragma unroll
            for (int ch = 0; ch < NLD; ++ch) {
                bf16x8 afr = *(const bf16x8*)(sgb + (mt * 16 + rl) * GSTR + ch * 32 + q * 8);
                acc[mt] = __builtin_amdgcn_mfma_f32_16x16x32_bf16(afr, wreg[k][ch], acc[mt], 0, 0, 0);
            }
    }

    // ---- folded-BN bias via mask MFMA: acc += M(mask 0/1) x BW
    if constexpr (BIAS) {
        bf16x8 bw = *(const bf16x8*)(BWt + ((size_t)br * 64 + colbase + rl) * 32 + q * 8);
        #pragma unroll
        for (int mt = 0; mt < 4; ++mt) {
            bf16x8 mf = *(const bf16x8*)(sM + (mt * 16 + rl) * 32 + q * 8);
            acc[mt] = __builtin_amdgcn_mfma_f32_16x16x32_bf16(mf, bw, acc[mt], 0, 0, 0);
        }
    }

    // ---- epilogue: LeakyReLU -> LDS tile (reuses ring) + BN partials
    __syncthreads();                       // all MFMA LDS reads done; reuse sG
    u16*   sO16 = (u16*)&sG[0][0];         // [64][72] bf16 tile (9216B)
    float* sO32 = (float*)&sG[0][0];       // [64][68] f32 tile (17408B, fits CIN=64 ring)
    float ps = 0.f, pss = 0.f;
    #pragma unroll
    for (int mt = 0; mt < 4; ++mt) {
        #pragma unroll
        for (int i = 0; i < 4; ++i) {
            float v = lrelu(acc[mt][i]);
            ps += v; pss += v * v;
            const int row = mt * 16 + q * 4 + i;
            if (outH) sO16[row * 72 + colbase + rl] = f2bf(v);
            else      sO32[row * 68 + colbase + rl] = v;
        }
    }
    ps  += __shfl_xor(ps, 16);  ps  += __shfl_xor(ps, 32);
    pss += __shfl_xor(pss, 16); pss += __shfl_xor(pss, 32);
    if (l < 16) { red[colbase + rl] = ps; red[64 + colbase + rl] = pss; }
    __syncthreads();

    // ---- coalesced full-line stores + sharded stat atomics
    if (outH) {
        #pragma unroll
        for (int p = 0; p < 2; ++p) {
            const int row = (tid >> 3) + p * 32, seg = tid & 7;
            uint4 v = *(const uint4*)(sO16 + row * 72 + seg * 8);
            *(uint4*)(outH + (size_t)(n0 + row) * 64 + seg * 8) = v;
        }
    } else {
        #pragma unroll
        for (int p = 0; p < 4; ++p) {
            const int row = (tid >> 4) + p * 16, seg = tid & 15;
            float4 v = *(const float4*)(sO32 + row * 68 + seg * 4);
            *(float4*)(outF + (size_t)(n0 + row) * 64 + seg * 4) = v;
        }
    }
    if (tid < 128) {
        const int shard = blockIdx.x & (NSHARD - 1);
        atomicAdd(st + shard * 512 + (tid >> 6) * 64 + (tid & 63), red[tid]);
    }
}

// b<144: WtA[br][k][d][c]=bf16(W[k][c][d]);  b in [144,208): zero sharded stats;
// b>=208: feats f32 -> bf16 (into feats16), grid-stride.
__global__ void prep0(const float* __restrict__ W1, const float* __restrict__ W2,
                      const float* __restrict__ feats,
                      u16* __restrict__ WtA, float* __restrict__ stats,
                      u16* __restrict__ feats16)
{
    const int b = blockIdx.x;
    const int t = threadIdx.x;
    if (b < 144) {
        const int i = b * 256 + t;                 // 2*9*64*32 = 36864 exactly
        const int brw = i / (KOFF * 64 * 32);
        const int r  = i % (KOFF * 64 * 32);
        const int k  = r / (64 * 32);
        const int r2 = r % (64 * 32);
        const int d  = r2 / 32, c = r2 % 32;
        const float* W = brw ? W2 : W1;
        WtA[i] = f2bf(W[((size_t)k * 32 + c) * 64 + d]);
        return;
    }
    if (b < 208) {                                 // 64*256 = 16384 = NSHARD*512
        stats[(b - 144) * 256 + t] = 0.f;
        return;
    }
    const int stride = (gridDim.x - 208) * 256;
    for (int i = (b - 208) * 256 + t; i < NVOX * 32 / 8; i += stride) {
        const float4 f0 = ((const float4*)feats)[i * 2];
        const float4 f1 = ((const float4*)feats)[i * 2 + 1];
        ((uint4*)feats16)[i] = make_uint4(pkbf(f0.x, f0.y), pkbf(f0.z, f0.w),
                                          pkbf(f1.x, f1.y), pkbf(f1.z, f1.w));
    }
}

// finalize stage-A BN (sum shards, in LDS) + fold into stage-B weights:
// WtB[br][k][d][c] = bf16(W[k][c][d]*a[c]); BWt[br][d][k(pad32)] = bf16(sum_c b'[c]*W[k][c][d])
__global__ void wprepB(const float* __restrict__ W12, const float* __restrict__ W3,
                       const float* __restrict__ stats,
                       const float* __restrict__ g0, const float* __restrict__ b0,
                       const float* __restrict__ g1, const float* __restrict__ b1,
                       u16* __restrict__ WtB, u16* __restrict__ BWt)
{
    __shared__ float sa[256];                 // [br][{a[64], b'[64]}]
    const int t = threadIdx.x;
    if (t < 128) {
        const int brw = t >> 6, d = t & 63;
        float s = 0.f, ss = 0.f;
        for (int sh = 0; sh < NSHARD; ++sh) {
            s  += stats[sh * 512 + brw * 128 + d];
            ss += stats[sh * 512 + brw * 128 + 64 + d];
        }
        const float* g = brw ? g1 : g0;
        const float* bb = brw ? b1 : b0;
        const float inv_n = 1.0f / (float)NVOX;
        float mu  = s * inv_n;
        float var = ss * inv_n - mu * mu;
        float a = g[d] * rsqrtf(var + BN_EPS);
        sa[brw * 128 + d] = a;
        sa[brw * 128 + 64 + d] = bb[d] - mu * a;
    }
    __syncthreads();
    const int i = blockIdx.x * 256 + t;
    if (i >= 2 * KOFF * 64) return;
    const int brw = i / (KOFF * 64);
    const int r  = i % (KOFF * 64);
    const int k  = r / 64, d = r % 64;
    const float* W = brw ? W3 : W12;
    const float* a = sa + brw * 128;
    const float* bb = a + 64;
    float bw = 0.f;
    u16* wrow = WtB + (((size_t)brw * KOFF + k) * 64 + d) * 64;
    #pragma unroll 8
    for (int c = 0; c < 64; ++c) {
        const float wv = W[((size_t)k * 64 + c) * 64 + d];
        wrow[c] = f2bf(wv * a[c]);
        bw += wv * bb[c];
    }
    u16* brow = BWt + ((size_t)brw * 64 + d) * 32;
    brow[k] = f2bf(bw);
    if (k == 0) {
        for (int kk = KOFF; kk < 32; ++kk) brow[kk] = 0;
    }
}

// finalize stage-B BN (sum shards) + out = aff2(ys) + aff3(yr), in place over yr (= d_out)
__global__ void combine_kernel(const u16* __restrict__ ys, float* __restrict__ yr,
                               const float* __restrict__ stats,
                               const float* __restrict__ g02, const float* __restrict__ b02,
                               const float* __restrict__ g2, const float* __restrict__ b2)
{
    __shared__ float sc[256];                 // [br][{a[64], b'[64]}]; br0=ys, br1=yr
    const int t = threadIdx.x;
    if (t < 128) {
        const int brw = t >> 6, d = t & 63;
        float s = 0.f, ss = 0.f;
        for (int sh = 0; sh < NSHARD; ++sh) {
            s  += stats[sh * 512 + 256 + brw * 128 + d];
            ss += stats[sh * 512 + 256 + brw * 128 + 64 + d];
        }
        const float* g = brw ? g2 : g02;
        const float* b = brw ? b2 : b02;
        const float inv_n = 1.0f / (float)NVOX;
        float mu  = s * inv_n;
        float var = ss * inv_n - mu * mu;
        float a = g[d] * rsqrtf(var + BN_EPS);
        sc[brw * 128 + d] = a;
        sc[brw * 128 + 64 + d] = b[d] - mu * a;
    }
    __syncthreads();
    const int total = NVOX * 64 / 4;
    for (int i = blockIdx.x * blockDim.x + t; i < total; i += gridDim.x * blockDim.x) {
        const int dq = (i & 15) * 4;
        ushort4 sh = reinterpret_cast<const ushort4*>(ys)[i];
        float4 r = reinterpret_cast<const float4*>(yr)[i];
        float4 a2 = *(const float4*)(sc + dq);
        float4 b2v = *(const float4*)(sc + 64 + dq);
        float4 a3 = *(const float4*)(sc + 128 + dq);
        float4 b3v = *(const float4*)(sc + 128 + 64 + dq);
        float4 o;
        o.x = fmaf(a2.x, bf2f(sh.x), b2v.x) + fmaf(a3.x, r.x, b3v.x);
        o.y = fmaf(a2.y, bf2f(sh.y), b2v.y) + fmaf(a3.y, r.y, b3v.y);
        o.z = fmaf(a2.z, bf2f(sh.z), b2v.z) + fmaf(a3.z, r.z, b3v.z);
        o.w = fmaf(a2.w, bf2f(sh.w), b2v.w) + fmaf(a3.w, r.w, b3v.w);
        reinterpret_cast<float4*>(yr)[i] = o;
    }
}

extern "C" void kernel_launch(void* const* d_in, const int* in_sizes, int n_in,
                              void* d_out, int out_size, void* d_ws, size_t ws_size,
                              hipStream_t stream) {
    const float* feats = (const float*)d_in[0];
    const float* W1    = (const float*)d_in[1];
    const float* W12   = (const float*)d_in[2];
    const float* W2    = (const float*)d_in[3];
    const float* W3    = (const float*)d_in[4];
    const float* g0  = (const float*)d_in[5];
    const float* b0  = (const float*)d_in[6];
    const float* g02 = (const float*)d_in[7];
    const float* b02 = (const float*)d_in[8];
    const float* g1  = (const float*)d_in[9];
    const float* b1  = (const float*)d_in[10];
    const float* g2  = (const float*)d_in[11];
    const float* b2  = (const float*)d_in[12];
    const int* nbrA  = (const int*)d_in[13];
    const int* maskA = (const int*)d_in[14];   // bool delivered as int32
    const int* nbrB  = (const int*)d_in[15];
    const int* maskB = (const int*)d_in[16];

    // ws layout: bf16 activations + bf16 weights + sharded f32 stats (~77 MB).
    // feats16 aliases ys: feats16 read only in stage A, ys written only in stage B.
    const size_t buf = (size_t)NVOX * 64;
    u16* y1  = (u16*)d_ws;
    u16* y2  = y1 + buf;
    u16* ys  = y2 + buf;
    u16* feats16 = ys;                   // alias (NVOX*32 u16)
    u16* WtA = ys + buf;                 // 2*9*64*32 = 36864
    u16* WtB = WtA + 2 * KOFF * 64 * 32; // 2*9*64*64 = 73728
    u16* BWt = WtB + 2 * KOFF * 64 * 64; // 2*64*32   = 4096
    float* stats = (float*)(BWt + 2 * 64 * 32);  // NSHARD x [4 x {sum[64],sumsq[64]}]
    float* outf  = (float*)d_out;        // stage-B resA output lives in d_out

    dim3 gA(NVOX / 64, 2);

    prep0<<<2000, 256, 0, stream>>>(W1, W2, feats, WtA, stats, feats16);

    // stage A: y1 = lrelu(conv(feats,nbrA,W1)); y2 = lrelu(conv(feats,nbrB,W2))
    conv_mfma<32, false><<<gA, 256, 0, stream>>>(
        feats16, feats16, nbrA, nbrB, maskA, maskB, WtA, nullptr,
        y1, y2, nullptr, nullptr, stats, stats + 128);

    wprepB<<<5, 256, 0, stream>>>(W12, W3, stats, g0, b0, g1, b1, WtB, BWt);

    // stage B: ys = lrelu(conv(bn(y1),nbrB,W12)); outf = lrelu(conv(bn(y2),nbrA,W3))
    conv_mfma<64, true><<<gA, 256, 0, stream>>>(
        y1, y2, nbrB, nbrA, maskB, maskA, WtB, BWt,
        ys, nullptr, nullptr, outf, stats + 256, stats + 384);

    combine_kernel<<<1024, 256, 0, stream>>>(ys, outf, stats, g02, b02, g2, b2);
}